// Round 15
// baseline (84.190 us; speedup 1.0000x reference)
//
#include <hip/hip_runtime.h>
#include <hip/hip_fp16.h>
#include <math.h>

#define NPTS 1024
#define DIM  128
#define BATCH 16
#define NCLOUD 32
#define BIGF 3.0e38f
#define BMAX 0xFFFFFFFFFFFFFFFFull

// ws layout (fast path):
//   [0, 1024)   : double mse_partials[128]   (written every call, no memset)
//   DEATHS_OFF  : float deaths[32][1024] (sorted)
//   D_OFF +64MB : fp16 D[32][1024][1024]
//   XBF_OFF+8MB : bf16 x[32][1024][128]
//   SQ_OFF      : f32 sq[32][1024]
//   BEST_OFF    : u64 best[32][1024]        (round-1 best from distmat)
//   CAND_OFF    : uint2 cand[32][16][1024]  (4 MB, stripe-major top-2 keys)
#define PART_OFF 0
#define DEATHS_OFF 1024
#define D_OFF 196608
#define XBF_OFF ((size_t)D_OFF + (size_t)NCLOUD * NPTS * NPTS * 2)
#define SQ_OFF   (XBF_OFF + (size_t)NCLOUD * NPTS * DIM * 2)
#define BEST_OFF (SQ_OFF + (size_t)NCLOUD * NPTS * 4)
#define CAND_OFF (BEST_OFF + (size_t)NCLOUD * NPTS * 8)
#define WS_NEED  (CAND_OFF + (size_t)NCLOUD * NPTS * 16 * 8)

typedef __attribute__((ext_vector_type(8))) short short8;
typedef __attribute__((ext_vector_type(4))) float f32x4;

__device__ __forceinline__ unsigned umin32(unsigned a, unsigned b) { return a < b ? a : b; }
__device__ __forceinline__ unsigned umax32(unsigned a, unsigned b) { return a > b ? a : b; }

__device__ __forceinline__ unsigned bfbits(float f) {
  unsigned u = __float_as_uint(f);
  return (u + 0x7FFFu + ((u >> 16) & 1u)) >> 16;  // RNE, finite inputs
}

// ---------------- fused prep + MSE-partials + state init ----------------
__global__ __launch_bounds__(256) void prep_mse(const float* __restrict__ x1,
                                                const float* __restrict__ x2,
                                                unsigned short* __restrict__ xbf,
                                                float* __restrict__ sqg,
                                                unsigned long long* __restrict__ best,
                                                double* __restrict__ partials) {
  const int b = blockIdx.x;
  const int s = blockIdx.y;
  const int tid = threadIdx.x;

  const int half = tid >> 7;
  const int r = s * 128 + (tid & 127);
  const int cloud = half * 16 + b;
  const float* xc = (half ? x2 : x1) + (size_t)b * NPTS * DIM;
  const float4* xr = (const float4*)(xc + (size_t)r * DIM);
  const float4* yr = (const float4*)(x2 + (size_t)b * NPTS * DIM + (size_t)r * DIM);
  uint4* orow = (uint4*)xbf + (size_t)cloud * NPTS * (DIM / 8) + (size_t)r * (DIM / 8);

  float mse_s = 0.f;
  float ax = 0.f, ay = 0.f, az = 0.f, aw = 0.f;
  #pragma unroll 4
  for (int m = 0; m < 32; m += 2) {
    float4 v0 = xr[m], v1 = xr[m + 1];
    ax = fmaf(v0.x, v0.x, ax); ay = fmaf(v0.y, v0.y, ay);
    az = fmaf(v0.z, v0.z, az); aw = fmaf(v0.w, v0.w, aw);
    ax = fmaf(v1.x, v1.x, ax); ay = fmaf(v1.y, v1.y, ay);
    az = fmaf(v1.z, v1.z, az); aw = fmaf(v1.w, v1.w, aw);
    uint4 o;
    o.x = bfbits(v0.x) | (bfbits(v0.y) << 16);
    o.y = bfbits(v0.z) | (bfbits(v0.w) << 16);
    o.z = bfbits(v1.x) | (bfbits(v1.y) << 16);
    o.w = bfbits(v1.z) | (bfbits(v1.w) << 16);
    orow[m >> 1] = o;
    if (half == 0) {
      float4 u0 = yr[m], u1 = yr[m + 1];
      float d0 = v0.x - u0.x, d1 = v0.y - u0.y, d2 = v0.z - u0.z, d3 = v0.w - u0.w;
      float e0 = v1.x - u1.x, e1 = v1.y - u1.y, e2 = v1.z - u1.z, e3 = v1.w - u1.w;
      mse_s += d0 * d0 + d1 * d1 + d2 * d2 + d3 * d3;
      mse_s += e0 * e0 + e1 * e1 + e2 * e2 + e3 * e3;
    }
  }
  sqg[cloud * NPTS + r] = (ax + ay) + (az + aw);
  best[cloud * NPTS + r] = BMAX;

  #pragma unroll
  for (int off = 32; off; off >>= 1) mse_s += __shfl_xor(mse_s, off);
  __shared__ float wsum[4];
  int lane = tid & 63, wid = tid >> 6;
  if (lane == 0) wsum[wid] = mse_s;
  __syncthreads();
  if (tid == 0)
    partials[b * 8 + s] = (double)(wsum[0] + wsum[1] + wsum[2] + wsum[3]);
}

// ---------------- MFMA distance matrix, LOWER-TRIANGLE blocks only ----------------
// LDS = exactly 32 KB (colred aliased into Ash after a post-MFMA barrier;
// sq read directly from global in the epilogue, L2-hot) -> 5 blocks/CU.
__global__ __launch_bounds__(256) void distmat_mfma(const unsigned short* __restrict__ xbf,
                                                    const float* __restrict__ sqg,
                                                    unsigned short* __restrict__ Dmat,
                                                    unsigned long long* __restrict__ best,
                                                    uint2* __restrict__ cand) {
  const int cloud = blockIdx.y;
  int t = blockIdx.x;
  int by = (int)((sqrtf(8.f * (float)t + 1.f) - 1.f) * 0.5f);
  while ((by + 1) * (by + 2) / 2 <= t) ++by;
  while (by * (by + 1) / 2 > t) --by;
  const int bx = t - by * (by + 1) / 2;
  const int i0 = by * 64;
  const int j0 = bx * 64;
  const bool diag = (bx == by);

  const int tid = threadIdx.x;
  const int lane = tid & 63, w = tid >> 6;
  const int l15 = lane & 15, kq = lane >> 4;

  __shared__ unsigned short Ash[64 * 128];   // 16 KB; aliased as colred post-MFMA
  __shared__ unsigned short Bsh[64 * 128];   // 16 KB -> total exactly 32 KB
  uint2* colred = (uint2*)Ash;               // [w*4+jt][l15] = (w*4+jt)*16+l15

  const uint4* xg = (const uint4*)xbf + (size_t)cloud * NPTS * (DIM / 8);
  uint4* A4 = (uint4*)Ash;
  uint4* B4 = (uint4*)Bsh;

  #pragma unroll
  for (int c = tid; c < 1024; c += 256) {
    int row = c >> 4, c16 = c & 15;
    int sidx = (row << 4) | (c16 ^ (row & 7));
    A4[sidx] = xg[((size_t)(i0 + row) << 4) | c16];
    B4[sidx] = xg[((size_t)(j0 + row) << 4) | c16];
  }
  __syncthreads();

  const int ar = w * 16 + l15;
  f32x4 acc[4];
  #pragma unroll
  for (int jt = 0; jt < 4; ++jt) acc[jt] = (f32x4){0.f, 0.f, 0.f, 0.f};

  #pragma unroll
  for (int kk = 0; kk < 4; ++kk) {
    int acol = (kk * 4 + kq) ^ (ar & 7);
    short8 a = *(const short8*)&A4[(ar << 4) | acol];
    #pragma unroll
    for (int jt = 0; jt < 4; ++jt) {
      int br = jt * 16 + l15;
      int bcol = (kk * 4 + kq) ^ (br & 7);
      short8 bf = *(const short8*)&B4[(br << 4) | bcol];
      acc[jt] = __builtin_amdgcn_mfma_f32_16x16x32_bf16(a, bf, acc[jt], 0, 0, 0);
    }
  }
  __syncthreads();  // all Ash/Bsh reads done -> colred alias safe

  unsigned short* Dc = Dmat + ((size_t)cloud << 20);
  unsigned long long* bestc = best + cloud * NPTS;
  const float* sqc = sqg + (size_t)cloud * NPTS;

  const int gib = i0 + w * 16 + kq * 4;
  // sq direct from global (L2-hot; identical values to the old LDS copies)
  float4 sqi4 = *(const float4*)(sqc + gib);
  float sqiv[4] = {sqi4.x, sqi4.y, sqi4.z, sqi4.w};
  float sqjv[4];
  #pragma unroll
  for (int jt = 0; jt < 4; ++jt) sqjv[jt] = sqc[j0 + jt * 16 + l15];

  unsigned k1[4]  = {0xFFFFFFFFu, 0xFFFFFFFFu, 0xFFFFFFFFu, 0xFFFFFFFFu};
  unsigned k2[4]  = {0xFFFFFFFFu, 0xFFFFFFFFu, 0xFFFFFFFFu, 0xFFFFFFFFu};
  unsigned ck1[4] = {0xFFFFFFFFu, 0xFFFFFFFFu, 0xFFFFFFFFu, 0xFFFFFFFFu};
  unsigned ck2[4] = {0xFFFFFFFFu, 0xFFFFFFFFu, 0xFFFFFFFFu, 0xFFFFFFFFu};

  #pragma unroll
  for (int jt = 0; jt < 4; ++jt) {
    int jl = jt * 16 + l15;
    int gj = j0 + jl;
    float sqj = sqjv[jt];
    unsigned hh[4];
    #pragma unroll
    for (int r = 0; r < 4; ++r) {
      int gi = gib + r;
      float d2 = sqiv[r] + sqj - 2.f * acc[jt][r];
      float d = sqrtf(fmaxf(d2, 0.f) + 1e-12f);
      unsigned h = (gi == gj) ? 0x7C00u : (unsigned)__half_as_ushort(__float2half(d));
      hh[r] = h;
      Dc[(size_t)gi * NPTS + gj] = (unsigned short)h;
      unsigned rkey = (h << 16) | (unsigned)gj;
      if (rkey < k1[r]) { k2[r] = k1[r]; k1[r] = rkey; }
      else if (rkey < k2[r]) k2[r] = rkey;
      unsigned ckey = (h << 16) | (unsigned)gi;
      if (ckey < ck1[jt]) { ck2[jt] = ck1[jt]; ck1[jt] = ckey; }
      else if (ckey < ck2[jt]) ck2[jt] = ckey;
    }
    if (!diag) {
      *(uint2*)&Dc[((size_t)gj << 10) + gib] =
          make_uint2(hh[0] | (hh[1] << 16), hh[2] | (hh[3] << 16));
    }
  }

  // ---- row-wise merge over the 16-lane col group; stripe bx, rows i-tile ----
  #pragma unroll
  for (int mask = 1; mask < 16; mask <<= 1) {
    #pragma unroll
    for (int r = 0; r < 4; ++r) {
      unsigned o1 = __shfl_xor(k1[r], mask);
      unsigned o2 = __shfl_xor(k2[r], mask);
      unsigned n1 = umin32(k1[r], o1);
      unsigned n2 = umin32(umax32(k1[r], o1), umin32(k2[r], o2));
      k1[r] = n1; k2[r] = n2;
    }
  }
  if (l15 == 0) {
    #pragma unroll
    for (int r = 0; r < 4; ++r) {
      unsigned gi = (unsigned)(gib + r);
      cand[(((size_t)(cloud * 16 + bx)) << 10) + gi] = make_uint2(k1[r], k2[r]);
      unsigned j = k1[r] & 0xFFFFu, hv = k1[r] >> 16;
      unsigned cmn = umin32(gi, j);
      unsigned cmx = gi + j - cmn;
      unsigned long long k64 =
          ((unsigned long long)hv << 20) | (unsigned long long)((cmn << 10) | cmx);
      atomicMin(&bestc[gi], k64);
    }
  }

  // ---- col-wise merge (off-diagonal only): stripe by, rows j-tile ----
  if (!diag) {
    #pragma unroll
    for (int mask = 16; mask < 64; mask <<= 1) {
      #pragma unroll
      for (int jt = 0; jt < 4; ++jt) {
        unsigned o1 = __shfl_xor(ck1[jt], mask);
        unsigned o2 = __shfl_xor(ck2[jt], mask);
        unsigned n1 = umin32(ck1[jt], o1);
        unsigned n2 = umin32(umax32(ck1[jt], o1), umin32(ck2[jt], o2));
        ck1[jt] = n1; ck2[jt] = n2;
      }
    }
    if (lane < 16) {
      #pragma unroll
      for (int jt = 0; jt < 4; ++jt)
        colred[(w * 4 + jt) * 16 + l15] = make_uint2(ck1[jt], ck2[jt]);
    }
    __syncthreads();
    if (tid < 64) {
      int c = tid;
      int jt = c >> 4, li = c & 15;
      uint2 a0 = colred[(0 * 4 + jt) * 16 + li], a1 = colred[(1 * 4 + jt) * 16 + li];
      uint2 a2 = colred[(2 * 4 + jt) * 16 + li], a3 = colred[(3 * 4 + jt) * 16 + li];
      unsigned m1 = a0.x, m2 = a0.y;
      #define MRG(v) { unsigned b1 = (v).x, b2 = (v).y; \
        unsigned n1 = umin32(m1, b1); \
        unsigned n2 = umin32(umax32(m1, b1), umin32(m2, b2)); \
        m1 = n1; m2 = n2; }
      MRG(a1) MRG(a2) MRG(a3)
      #undef MRG
      unsigned gj = (unsigned)(j0 + c);
      cand[(((size_t)(cloud * 16 + by)) << 10) + gj] = make_uint2(m1, m2);
      unsigned j = m1 & 0xFFFFu, hv = m1 >> 16;
      unsigned cmn = umin32(gj, j);
      unsigned cmx = gj + j - cmn;
      unsigned long long k64 =
          ((unsigned long long)hv << 20) | (unsigned long long)((cmn << 10) | cmx);
      atomicMin(&bestc[gj], k64);
    }
  }
}

// ---------------- single-block-per-cloud Boruvka solve + fused hybrid sort ----------------
// Round-12 verified: component-best filter gates the fallback rescans.
__global__ __launch_bounds__(1024) void boruvka_solve(const unsigned short* __restrict__ Dmat,
                                                      const uint2* __restrict__ cand,
                                                      const unsigned long long* __restrict__ best_init,
                                                      float* __restrict__ deaths_out) {
  const int cloud = blockIdx.x;
  const int tid = threadIdx.x;
  const int lane = tid & 63, wid = tid >> 6;

  __shared__ unsigned short comp16[NPTS];
  __shared__ unsigned short par[NPTS];
  __shared__ unsigned long long best64[NPTS];
  __shared__ float dl[NPTS];
  __shared__ unsigned short fb[NPTS];
  __shared__ unsigned nfb_sh, dcnt_sh;

  uint2 c[16];
  const uint2* candc = cand + ((size_t)cloud << 14);
  #pragma unroll
  for (int s = 0; s < 16; ++s) c[s] = candc[(s << 10) + tid];

  comp16[tid] = (unsigned short)tid;
  par[tid] = (unsigned short)tid;
  best64[tid] = best_init[cloud * NPTS + tid];
  dl[tid] = BIGF;
  if (tid == 0) { dcnt_sh = 0; nfb_sh = 0; }
  __syncthreads();

  const uint4* p = (const uint4*)(Dmat + ((size_t)cloud << 20));
  const unsigned jb0 = (unsigned)(lane << 3), jb1 = 512u + jb0;

  for (int rnd = 0; rnd < 11; ++rnd) {
    if (rnd > 0) {
      unsigned ci = comp16[tid];
      unsigned e = 0xFFFFFFFFu;
      unsigned bw = 0xFFFFu;
      #pragma unroll
      for (int s = 0; s < 16; ++s) {
        unsigned j1 = c[s].x & 0xFFFFu, j2 = c[s].y & 0xFFFFu;
        bool o1 = ((unsigned)comp16[j1] != ci);
        bool o2 = ((unsigned)comp16[j2] != ci);
        unsigned es = o1 ? c[s].x : (o2 ? c[s].y : 0xFFFFFFFFu);
        unsigned bs = (!o1 && !o2) ? (c[s].y >> 16) : 0xFFFFu;
        e = umin32(e, es);
        bw = umin32(bw, bs);
      }
      if (e != 0xFFFFFFFFu) {
        unsigned j = e & 0xFFFFu, hv = e >> 16;
        unsigned cmn = umin32((unsigned)tid, j);
        unsigned cmx = (unsigned)tid + j - cmn;
        unsigned long long k64 =
            ((unsigned long long)hv << 20) | (unsigned long long)((cmn << 10) | cmx);
        atomicMin(&best64[ci], k64);
      }
      __syncthreads();  // B1: all exact candidates applied

      unsigned bestw = (unsigned)((best64[ci] >> 20) & 0xFFFFu);
      if (bw <= bestw) {
        unsigned slot = atomicAdd(&nfb_sh, 1u);
        fb[slot] = (unsigned short)tid;
      }
      __syncthreads();  // B2: nfb + fb visible

      unsigned nfb = nfb_sh;
      if (nfb) {
        unsigned cj[16];
        #pragma unroll
        for (int q = 0; q < 8; ++q) cj[q] = comp16[jb0 + q];
        #pragma unroll
        for (int q = 0; q < 8; ++q) cj[8 + q] = comp16[jb1 + q];
        for (unsigned k = (unsigned)wid; k < nfb; k += 16) {
          int frow = fb[k];
          unsigned fci = (unsigned)comp16[frow];
          uint4 ra = p[frow * 128 + lane];
          uint4 rb = p[frow * 128 + 64 + lane];
          unsigned key = 0xFFFFFFFFu;
          #define ENT(word, cl, ch, jb) { \
            unsigned klo = ((word) << 16) | (jb); \
            unsigned khi = ((word) & 0xFFFF0000u) | ((jb) + 1); \
            key = umin32(key, (cl) == fci ? 0xFFFFFFFFu : klo); \
            key = umin32(key, (ch) == fci ? 0xFFFFFFFFu : khi); }
          ENT(ra.x, cj[0],  cj[1],  jb0 + 0) ENT(ra.y, cj[2],  cj[3],  jb0 + 2)
          ENT(ra.z, cj[4],  cj[5],  jb0 + 4) ENT(ra.w, cj[6],  cj[7],  jb0 + 6)
          ENT(rb.x, cj[8],  cj[9],  jb1 + 0) ENT(rb.y, cj[10], cj[11], jb1 + 2)
          ENT(rb.z, cj[12], cj[13], jb1 + 4) ENT(rb.w, cj[14], cj[15], jb1 + 6)
          #undef ENT
          #define DPPMIN(ctrl) { \
            unsigned tv = (unsigned)__builtin_amdgcn_update_dpp((int)key, (int)key, (ctrl), 0xF, 0xF, false); \
            key = umin32(key, tv); }
          DPPMIN(0x111) DPPMIN(0x112) DPPMIN(0x114) DPPMIN(0x118)
          DPPMIN(0x142) DPPMIN(0x143)
          #undef DPPMIN
          if (lane == 63 && key != 0xFFFFFFFFu) {
            unsigned wv = key >> 16, v = key & 0xFFFFu;
            unsigned cmn = umin32((unsigned)frow, v);
            unsigned cmx = (unsigned)frow + v - cmn;
            unsigned long long k64 =
                ((unsigned long long)wv << 20) | (unsigned long long)((cmn << 10) | cmx);
            atomicMin(&best64[fci], k64);
          }
        }
        __syncthreads();  // B3: fallback atomics visible
      }
    }

    // ---- merge: hook, 2-cycle break, append ----
    unsigned long long bk = best64[tid];
    unsigned cold = comp16[tid];
    unsigned partner = (unsigned)tid;
    unsigned wb = 0;
    if (cold == (unsigned)tid && bk != BMAX) {
      wb = (unsigned)(bk >> 20) & 0xFFFFu;
      unsigned cmin = (unsigned)(bk >> 10) & 1023u;
      unsigned cmax = (unsigned)bk & 1023u;
      unsigned ca = comp16[cmin], cb = comp16[cmax];
      partner = (ca == (unsigned)tid) ? cb : ca;
      par[tid] = (unsigned short)partner;
    }
    __syncthreads();  // B4: hooks visible
    unsigned pp = par[partner];
    bool twoc = (partner != (unsigned)tid) && (pp == (unsigned)tid);
    bool winner = twoc && ((unsigned)tid < partner);
    bool append = (partner != (unsigned)tid) && !winner;
    __syncthreads();  // B5: all pp reads done before winner-fix writes
    if (winner) par[tid] = (unsigned short)tid;
    if (append) {
      unsigned slot = atomicAdd(&dcnt_sh, 1u);
      dl[slot] = __half2float(__ushort_as_half((unsigned short)wb));
    }
    __syncthreads();  // B6: par final for chase; dcnt visible
    if (dcnt_sh == NPTS - 1) break;

    unsigned x = cold;
    unsigned px = par[x];
    while (px != x) { x = px; px = par[x]; }
    __syncthreads();  // B7: chases done before state rewrite
    comp16[tid] = (unsigned short)x;
    par[tid] = (unsigned short)tid;
    best64[tid] = BMAX;
    if (tid == 0) nfb_sh = 0;
    __syncthreads();  // B8: state ready for next round
  }
  __syncthreads();

  // ---- hybrid bitonic sort: jj<64 via shfl, jj>=64 via LDS ----
  float v = dl[tid];
  for (int k = 2; k <= NPTS; k <<= 1) {
    bool up = ((tid & k) == 0);
    for (int jj = k >> 1; jj > 0; jj >>= 1) {
      float pv;
      if (jj >= 64) {
        __syncthreads();
        dl[tid] = v;
        __syncthreads();
        pv = dl[tid ^ jj];
      } else {
        pv = __shfl_xor(v, jj);
      }
      bool lower = ((tid & jj) == 0);
      v = (lower == up) ? fminf(v, pv) : fmaxf(v, pv);
    }
  }
  deaths_out[(size_t)cloud * NPTS + tid] = v;
}

// ---------------- fallback MSE kernel (small ws path) ----------------
__global__ __launch_bounds__(256) void mse_kernel(const float* __restrict__ a,
                                                  const float* __restrict__ b,
                                                  double* __restrict__ acc, int n4) {
  int i = blockIdx.x * blockDim.x + threadIdx.x;
  int stride = gridDim.x * blockDim.x;
  const float4* a4 = (const float4*)a;
  const float4* b4 = (const float4*)b;
  float s = 0.f;
  for (int k = i; k < n4; k += stride) {
    float4 va = a4[k], vb = b4[k];
    float dx = va.x - vb.x, dy = va.y - vb.y, dz = va.z - vb.z, dw = va.w - vb.w;
    s += dx * dx + dy * dy + dz * dz + dw * dw;
  }
  #pragma unroll
  for (int off = 32; off; off >>= 1) s += __shfl_xor(s, off);
  __shared__ float wsum[4];
  int lane = threadIdx.x & 63, wid = threadIdx.x >> 6;
  if (lane == 0) wsum[wid] = s;
  __syncthreads();
  if (threadIdx.x == 0)
    atomicAdd(acc, (double)(wsum[0] + wsum[1] + wsum[2] + wsum[3]));
}

// ---------------- fallback: fused Prim+sort from x (small ws) ----------------
__global__ __launch_bounds__(1024) void prim_kernel(const float* __restrict__ x1,
                                                    const float* __restrict__ x2,
                                                    float* __restrict__ sorted_out) {
  const int cloud = blockIdx.x;
  const int b = cloud & (BATCH - 1);
  const int src = cloud >> 4;
  const float* xbase = (src ? x2 : x1) + (size_t)b * NPTS * DIM;
  const int j = threadIdx.x;

  __shared__ float xi_sh[DIM];
  __shared__ float sq_sh[NPTS];
  __shared__ float redw[16];
  __shared__ int   redi[16];
  __shared__ float deaths[NPTS];

  const float4* xr = (const float4*)(xbase + (size_t)j * DIM);
  {
    float ax = 0.f, ay = 0.f, az = 0.f, aw = 0.f;
    #pragma unroll 8
    for (int m = 0; m < DIM / 4; ++m) {
      float4 v = xr[m];
      ax = fmaf(v.x, v.x, ax); ay = fmaf(v.y, v.y, ay);
      az = fmaf(v.z, v.z, az); aw = fmaf(v.w, v.w, aw);
    }
    sq_sh[j] = (ax + ay) + (az + aw);
  }
  const float sqj = sq_sh[j];

  float mind = BIGF;
  bool in_tree = (j == 0);
  int  cur = 0;

  for (int t = 0; t < NPTS - 1; ++t) {
    if (threadIdx.x < DIM / 4)
      ((float4*)xi_sh)[threadIdx.x] = ((const float4*)(xbase + (size_t)cur * DIM))[threadIdx.x];
    __syncthreads();

    const float4* xi4 = (const float4*)xi_sh;
    float ax = 0.f, ay = 0.f, az = 0.f, aw = 0.f;
    #pragma unroll 8
    for (int m = 0; m < DIM / 4; ++m) {
      float4 v = xr[m];
      float4 u = xi4[m];
      ax = fmaf(v.x, u.x, ax); ay = fmaf(v.y, u.y, ay);
      az = fmaf(v.z, u.z, az); aw = fmaf(v.w, u.w, aw);
    }
    float dot = (ax + ay) + (az + aw);
    float d2 = sq_sh[cur] + sqj - 2.f * dot;
    float d = sqrtf(fmaxf(d2, 0.f) + 1e-12f);
    mind = in_tree ? BIGF : fminf(mind, d);

    float w = mind;
    int idx = j;
    #pragma unroll
    for (int off = 32; off; off >>= 1) {
      float w2 = __shfl_xor(w, off);
      int i2 = __shfl_xor(idx, off);
      if (w2 < w || (w2 == w && i2 < idx)) { w = w2; idx = i2; }
    }
    int lane = j & 63, wid = j >> 6;
    if (lane == 0) { redw[wid] = w; redi[wid] = idx; }
    __syncthreads();

    float cw = redw[0];
    int ci = redi[0];
    #pragma unroll
    for (int q = 1; q < 16; ++q) {
      float w2 = redw[q]; int i2 = redi[q];
      if (w2 < cw || (w2 == cw && i2 < ci)) { cw = w2; ci = i2; }
    }
    if (j == ci) in_tree = true;
    if (j == 0)  deaths[t] = cw;
    cur = ci;
  }

  if (threadIdx.x == 0) deaths[NPTS - 1] = BIGF;
  __syncthreads();

  for (int k = 2; k <= NPTS; k <<= 1) {
    for (int jj = k >> 1; jj > 0; jj >>= 1) {
      int i = threadIdx.x;
      int l = i ^ jj;
      if (l > i) {
        float va = deaths[i], vb = deaths[l];
        bool up = ((i & k) == 0);
        if ((va > vb) == up) { deaths[i] = vb; deaths[l] = va; }
      }
      __syncthreads();
    }
  }
  sorted_out[(size_t)cloud * NPTS + threadIdx.x] = deaths[threadIdx.x];
}

// ---------------- final combine (sums the 128 MSE partials deterministically) ----------------
__global__ __launch_bounds__(1024) void final_kernel(const double* __restrict__ partials,
                                                     const float* __restrict__ sorted,
                                                     float* __restrict__ out, int npart) {
  int wid = threadIdx.x >> 6;
  int lane = threadIdx.x & 63;
  const float* s1 = sorted + (size_t)wid * NPTS;
  const float* s2 = sorted + (size_t)(BATCH + wid) * NPTS;
  float s = 0.f;
  for (int k = lane; k < NPTS; k += 64) {
    float dlt = s1[k] - s2[k];
    s += dlt * dlt;
  }
  #pragma unroll
  for (int off = 32; off; off >>= 1) s += __shfl_xor(s, off);
  __shared__ float part[16];
  __shared__ double dsum[128];
  if (threadIdx.x < (unsigned)npart) dsum[threadIdx.x] = partials[threadIdx.x];
  if (lane == 0) part[wid] = sqrtf(s);
  __syncthreads();
  if (threadIdx.x == 0) {
    float topo = 0.f;
    #pragma unroll
    for (int q = 0; q < 16; ++q) topo += part[q];
    double msum = 0.0;
    for (int q = 0; q < npart; ++q) msum += dsum[q];
    float mse = (float)(msum / (double)((size_t)BATCH * NPTS * DIM));
    out[0] = 1.0f * mse + 0.1f * topo;
  }
}

extern "C" void kernel_launch(void* const* d_in, const int* in_sizes, int n_in,
                              void* d_out, int out_size, void* d_ws, size_t ws_size,
                              hipStream_t stream) {
  const float* x1 = (const float*)d_in[0];
  const float* x2 = (const float*)d_in[1];
  double* partials = (double*)((char*)d_ws + PART_OFF);
  float* deaths    = (float*)((char*)d_ws + DEATHS_OFF);
  float* out       = (float*)d_out;

  if (ws_size >= WS_NEED) {
    unsigned short* Dmat = (unsigned short*)((char*)d_ws + D_OFF);
    unsigned short* xbf  = (unsigned short*)((char*)d_ws + XBF_OFF);
    float* sqg           = (float*)((char*)d_ws + SQ_OFF);
    unsigned long long* best = (unsigned long long*)((char*)d_ws + BEST_OFF);
    uint2* cand          = (uint2*)((char*)d_ws + CAND_OFF);

    prep_mse<<<dim3(BATCH, 8), 256, 0, stream>>>(x1, x2, xbf, sqg, best, partials);
    distmat_mfma<<<dim3(136, NCLOUD), 256, 0, stream>>>(xbf, sqg, Dmat, best, cand);
    boruvka_solve<<<NCLOUD, 1024, 0, stream>>>(Dmat, cand, best, deaths);
    final_kernel<<<1, 1024, 0, stream>>>(partials, deaths, out, 128);
  } else {
    hipMemsetAsync(d_ws, 0, 64, stream);
    double* mse_acc = (double*)d_ws;
    int n4 = (BATCH * NPTS * DIM) / 4;
    mse_kernel<<<1024, 256, 0, stream>>>(x1, x2, mse_acc, n4);
    prim_kernel<<<NCLOUD, 1024, 0, stream>>>(x1, x2, deaths);
    final_kernel<<<1, 1024, 0, stream>>>(mse_acc, deaths, out, 1);
  }
}

// Round 16
// 81.129 us; speedup vs baseline: 1.0377x; 1.0377x over previous
//
#include <hip/hip_runtime.h>
#include <hip/hip_fp16.h>
#include <math.h>

#define NPTS 1024
#define DIM  128
#define BATCH 16
#define NCLOUD 32
#define BIGF 3.0e38f
#define BMAX 0xFFFFFFFFFFFFFFFFull

// ws layout (fast path):
//   [0, 1024)   : double mse_partials[128]   (written every call, no memset)
//   DEATHS_OFF  : float deaths[32][1024] (sorted)
//   D_OFF +64MB : fp16 D[32][1024][1024]
//   XBF_OFF+8MB : bf16 x[32][1024][128]
//   SQ_OFF      : f32 sq[32][1024]
//   BEST_OFF    : u64 best[32][1024]        (round-1 best from distmat)
//   CAND_OFF    : uint2 cand[32][16][1024]  (4 MB, stripe-major top-2 keys)
#define PART_OFF 0
#define DEATHS_OFF 1024
#define D_OFF 196608
#define XBF_OFF ((size_t)D_OFF + (size_t)NCLOUD * NPTS * NPTS * 2)
#define SQ_OFF   (XBF_OFF + (size_t)NCLOUD * NPTS * DIM * 2)
#define BEST_OFF (SQ_OFF + (size_t)NCLOUD * NPTS * 4)
#define CAND_OFF (BEST_OFF + (size_t)NCLOUD * NPTS * 8)
#define WS_NEED  (CAND_OFF + (size_t)NCLOUD * NPTS * 16 * 8)

typedef __attribute__((ext_vector_type(8))) short short8;
typedef __attribute__((ext_vector_type(4))) float f32x4;

__device__ __forceinline__ unsigned umin32(unsigned a, unsigned b) { return a < b ? a : b; }
__device__ __forceinline__ unsigned umax32(unsigned a, unsigned b) { return a > b ? a : b; }

__device__ __forceinline__ unsigned bfbits(float f) {
  unsigned u = __float_as_uint(f);
  return (u + 0x7FFFu + ((u >> 16) & 1u)) >> 16;  // RNE, finite inputs
}

// ---------------- fused prep + MSE-partials + state init ----------------
// grid (NCLOUD, 8) x 128 thr: one block per (cloud, 128-row slice) -> 256
// blocks (full GPU). MSE partial layout/bits identical to the 2-wave sums
// of the previous version (x1-clouds only).
__global__ __launch_bounds__(128) void prep_mse(const float* __restrict__ x1,
                                                const float* __restrict__ x2,
                                                unsigned short* __restrict__ xbf,
                                                float* __restrict__ sqg,
                                                unsigned long long* __restrict__ best,
                                                double* __restrict__ partials) {
  const int cloud = blockIdx.x;
  const int s = blockIdx.y;
  const int tid = threadIdx.x;

  const int half = cloud >> 4;
  const int b = cloud & (BATCH - 1);
  const int r = s * 128 + tid;
  const float* xc = (half ? x2 : x1) + (size_t)b * NPTS * DIM;
  const float4* xr = (const float4*)(xc + (size_t)r * DIM);
  const float4* yr = (const float4*)(x2 + (size_t)b * NPTS * DIM + (size_t)r * DIM);
  uint4* orow = (uint4*)xbf + (size_t)cloud * NPTS * (DIM / 8) + (size_t)r * (DIM / 8);

  float mse_s = 0.f;
  float ax = 0.f, ay = 0.f, az = 0.f, aw = 0.f;
  #pragma unroll 4
  for (int m = 0; m < 32; m += 2) {
    float4 v0 = xr[m], v1 = xr[m + 1];
    ax = fmaf(v0.x, v0.x, ax); ay = fmaf(v0.y, v0.y, ay);
    az = fmaf(v0.z, v0.z, az); aw = fmaf(v0.w, v0.w, aw);
    ax = fmaf(v1.x, v1.x, ax); ay = fmaf(v1.y, v1.y, ay);
    az = fmaf(v1.z, v1.z, az); aw = fmaf(v1.w, v1.w, aw);
    uint4 o;
    o.x = bfbits(v0.x) | (bfbits(v0.y) << 16);
    o.y = bfbits(v0.z) | (bfbits(v0.w) << 16);
    o.z = bfbits(v1.x) | (bfbits(v1.y) << 16);
    o.w = bfbits(v1.z) | (bfbits(v1.w) << 16);
    orow[m >> 1] = o;
    if (half == 0) {
      float4 u0 = yr[m], u1 = yr[m + 1];
      float d0 = v0.x - u0.x, d1 = v0.y - u0.y, d2 = v0.z - u0.z, d3 = v0.w - u0.w;
      float e0 = v1.x - u1.x, e1 = v1.y - u1.y, e2 = v1.z - u1.z, e3 = v1.w - u1.w;
      mse_s += d0 * d0 + d1 * d1 + d2 * d2 + d3 * d3;
      mse_s += e0 * e0 + e1 * e1 + e2 * e2 + e3 * e3;
    }
  }
  sqg[cloud * NPTS + r] = (ax + ay) + (az + aw);
  best[cloud * NPTS + r] = BMAX;

  if (half == 0) {
    #pragma unroll
    for (int off = 32; off; off >>= 1) mse_s += __shfl_xor(mse_s, off);
    __shared__ float wsum[2];
    int lane = tid & 63, wid = tid >> 6;
    if (lane == 0) wsum[wid] = mse_s;
    __syncthreads();
    if (tid == 0)
      partials[b * 8 + s] = (double)(wsum[0] + wsum[1]);
  }
}

// ---------------- MFMA distance matrix, LOWER-TRIANGLE blocks only ----------------
// LDS = exactly 32 KB (colred aliased into Ash after a post-MFMA barrier;
// sq read directly from global in the epilogue, L2-hot).
__global__ __launch_bounds__(256) void distmat_mfma(const unsigned short* __restrict__ xbf,
                                                    const float* __restrict__ sqg,
                                                    unsigned short* __restrict__ Dmat,
                                                    unsigned long long* __restrict__ best,
                                                    uint2* __restrict__ cand) {
  const int cloud = blockIdx.y;
  int t = blockIdx.x;
  int by = (int)((sqrtf(8.f * (float)t + 1.f) - 1.f) * 0.5f);
  while ((by + 1) * (by + 2) / 2 <= t) ++by;
  while (by * (by + 1) / 2 > t) --by;
  const int bx = t - by * (by + 1) / 2;
  const int i0 = by * 64;
  const int j0 = bx * 64;
  const bool diag = (bx == by);

  const int tid = threadIdx.x;
  const int lane = tid & 63, w = tid >> 6;
  const int l15 = lane & 15, kq = lane >> 4;

  __shared__ unsigned short Ash[64 * 128];   // 16 KB; aliased as colred post-MFMA
  __shared__ unsigned short Bsh[64 * 128];   // 16 KB -> total exactly 32 KB
  uint2* colred = (uint2*)Ash;               // [w*4+jt][l15] = (w*4+jt)*16+l15

  const uint4* xg = (const uint4*)xbf + (size_t)cloud * NPTS * (DIM / 8);
  uint4* A4 = (uint4*)Ash;
  uint4* B4 = (uint4*)Bsh;

  #pragma unroll
  for (int c = tid; c < 1024; c += 256) {
    int row = c >> 4, c16 = c & 15;
    int sidx = (row << 4) | (c16 ^ (row & 7));
    A4[sidx] = xg[((size_t)(i0 + row) << 4) | c16];
    B4[sidx] = xg[((size_t)(j0 + row) << 4) | c16];
  }
  __syncthreads();

  const int ar = w * 16 + l15;
  f32x4 acc[4];
  #pragma unroll
  for (int jt = 0; jt < 4; ++jt) acc[jt] = (f32x4){0.f, 0.f, 0.f, 0.f};

  #pragma unroll
  for (int kk = 0; kk < 4; ++kk) {
    int acol = (kk * 4 + kq) ^ (ar & 7);
    short8 a = *(const short8*)&A4[(ar << 4) | acol];
    #pragma unroll
    for (int jt = 0; jt < 4; ++jt) {
      int br = jt * 16 + l15;
      int bcol = (kk * 4 + kq) ^ (br & 7);
      short8 bf = *(const short8*)&B4[(br << 4) | bcol];
      acc[jt] = __builtin_amdgcn_mfma_f32_16x16x32_bf16(a, bf, acc[jt], 0, 0, 0);
    }
  }
  __syncthreads();  // all Ash/Bsh reads done -> colred alias safe

  unsigned short* Dc = Dmat + ((size_t)cloud << 20);
  unsigned long long* bestc = best + cloud * NPTS;
  const float* sqc = sqg + (size_t)cloud * NPTS;

  const int gib = i0 + w * 16 + kq * 4;
  float4 sqi4 = *(const float4*)(sqc + gib);
  float sqiv[4] = {sqi4.x, sqi4.y, sqi4.z, sqi4.w};
  float sqjv[4];
  #pragma unroll
  for (int jt = 0; jt < 4; ++jt) sqjv[jt] = sqc[j0 + jt * 16 + l15];

  unsigned k1[4]  = {0xFFFFFFFFu, 0xFFFFFFFFu, 0xFFFFFFFFu, 0xFFFFFFFFu};
  unsigned k2[4]  = {0xFFFFFFFFu, 0xFFFFFFFFu, 0xFFFFFFFFu, 0xFFFFFFFFu};
  unsigned ck1[4] = {0xFFFFFFFFu, 0xFFFFFFFFu, 0xFFFFFFFFu, 0xFFFFFFFFu};
  unsigned ck2[4] = {0xFFFFFFFFu, 0xFFFFFFFFu, 0xFFFFFFFFu, 0xFFFFFFFFu};

  #pragma unroll
  for (int jt = 0; jt < 4; ++jt) {
    int jl = jt * 16 + l15;
    int gj = j0 + jl;
    float sqj = sqjv[jt];
    unsigned hh[4];
    #pragma unroll
    for (int r = 0; r < 4; ++r) {
      int gi = gib + r;
      float d2 = sqiv[r] + sqj - 2.f * acc[jt][r];
      float d = sqrtf(fmaxf(d2, 0.f) + 1e-12f);
      unsigned h = (gi == gj) ? 0x7C00u : (unsigned)__half_as_ushort(__float2half(d));
      hh[r] = h;
      Dc[(size_t)gi * NPTS + gj] = (unsigned short)h;
      unsigned rkey = (h << 16) | (unsigned)gj;
      if (rkey < k1[r]) { k2[r] = k1[r]; k1[r] = rkey; }
      else if (rkey < k2[r]) k2[r] = rkey;
      unsigned ckey = (h << 16) | (unsigned)gi;
      if (ckey < ck1[jt]) { ck2[jt] = ck1[jt]; ck1[jt] = ckey; }
      else if (ckey < ck2[jt]) ck2[jt] = ckey;
    }
    if (!diag) {
      *(uint2*)&Dc[((size_t)gj << 10) + gib] =
          make_uint2(hh[0] | (hh[1] << 16), hh[2] | (hh[3] << 16));
    }
  }

  // ---- row-wise merge over the 16-lane col group; stripe bx, rows i-tile ----
  #pragma unroll
  for (int mask = 1; mask < 16; mask <<= 1) {
    #pragma unroll
    for (int r = 0; r < 4; ++r) {
      unsigned o1 = __shfl_xor(k1[r], mask);
      unsigned o2 = __shfl_xor(k2[r], mask);
      unsigned n1 = umin32(k1[r], o1);
      unsigned n2 = umin32(umax32(k1[r], o1), umin32(k2[r], o2));
      k1[r] = n1; k2[r] = n2;
    }
  }
  if (l15 == 0) {
    #pragma unroll
    for (int r = 0; r < 4; ++r) {
      unsigned gi = (unsigned)(gib + r);
      cand[(((size_t)(cloud * 16 + bx)) << 10) + gi] = make_uint2(k1[r], k2[r]);
      unsigned j = k1[r] & 0xFFFFu, hv = k1[r] >> 16;
      unsigned cmn = umin32(gi, j);
      unsigned cmx = gi + j - cmn;
      unsigned long long k64 =
          ((unsigned long long)hv << 20) | (unsigned long long)((cmn << 10) | cmx);
      atomicMin(&bestc[gi], k64);
    }
  }

  // ---- col-wise merge (off-diagonal only): stripe by, rows j-tile ----
  if (!diag) {
    #pragma unroll
    for (int mask = 16; mask < 64; mask <<= 1) {
      #pragma unroll
      for (int jt = 0; jt < 4; ++jt) {
        unsigned o1 = __shfl_xor(ck1[jt], mask);
        unsigned o2 = __shfl_xor(ck2[jt], mask);
        unsigned n1 = umin32(ck1[jt], o1);
        unsigned n2 = umin32(umax32(ck1[jt], o1), umin32(ck2[jt], o2));
        ck1[jt] = n1; ck2[jt] = n2;
      }
    }
    if (lane < 16) {
      #pragma unroll
      for (int jt = 0; jt < 4; ++jt)
        colred[(w * 4 + jt) * 16 + l15] = make_uint2(ck1[jt], ck2[jt]);
    }
    __syncthreads();
    if (tid < 64) {
      int c = tid;
      int jt = c >> 4, li = c & 15;
      uint2 a0 = colred[(0 * 4 + jt) * 16 + li], a1 = colred[(1 * 4 + jt) * 16 + li];
      uint2 a2 = colred[(2 * 4 + jt) * 16 + li], a3 = colred[(3 * 4 + jt) * 16 + li];
      unsigned m1 = a0.x, m2 = a0.y;
      #define MRG(v) { unsigned b1 = (v).x, b2 = (v).y; \
        unsigned n1 = umin32(m1, b1); \
        unsigned n2 = umin32(umax32(m1, b1), umin32(m2, b2)); \
        m1 = n1; m2 = n2; }
      MRG(a1) MRG(a2) MRG(a3)
      #undef MRG
      unsigned gj = (unsigned)(j0 + c);
      cand[(((size_t)(cloud * 16 + by)) << 10) + gj] = make_uint2(m1, m2);
      unsigned j = m1 & 0xFFFFu, hv = m1 >> 16;
      unsigned cmn = umin32(gj, j);
      unsigned cmx = gj + j - cmn;
      unsigned long long k64 =
          ((unsigned long long)hv << 20) | (unsigned long long)((cmn << 10) | cmx);
      atomicMin(&bestc[gj], k64);
    }
  }
}

// ---------------- single-block-per-cloud Boruvka solve + fused hybrid sort ----------------
// Round-12 verified: component-best filter gates the fallback rescans.
__global__ __launch_bounds__(1024) void boruvka_solve(const unsigned short* __restrict__ Dmat,
                                                      const uint2* __restrict__ cand,
                                                      const unsigned long long* __restrict__ best_init,
                                                      float* __restrict__ deaths_out) {
  const int cloud = blockIdx.x;
  const int tid = threadIdx.x;
  const int lane = tid & 63, wid = tid >> 6;

  __shared__ unsigned short comp16[NPTS];
  __shared__ unsigned short par[NPTS];
  __shared__ unsigned long long best64[NPTS];
  __shared__ float dl[NPTS];
  __shared__ unsigned short fb[NPTS];
  __shared__ unsigned nfb_sh, dcnt_sh;

  uint2 c[16];
  const uint2* candc = cand + ((size_t)cloud << 14);
  #pragma unroll
  for (int s = 0; s < 16; ++s) c[s] = candc[(s << 10) + tid];

  comp16[tid] = (unsigned short)tid;
  par[tid] = (unsigned short)tid;
  best64[tid] = best_init[cloud * NPTS + tid];
  dl[tid] = BIGF;
  if (tid == 0) { dcnt_sh = 0; nfb_sh = 0; }
  __syncthreads();

  const uint4* p = (const uint4*)(Dmat + ((size_t)cloud << 20));
  const unsigned jb0 = (unsigned)(lane << 3), jb1 = 512u + jb0;

  for (int rnd = 0; rnd < 11; ++rnd) {
    if (rnd > 0) {
      unsigned ci = comp16[tid];
      unsigned e = 0xFFFFFFFFu;
      unsigned bw = 0xFFFFu;
      #pragma unroll
      for (int s = 0; s < 16; ++s) {
        unsigned j1 = c[s].x & 0xFFFFu, j2 = c[s].y & 0xFFFFu;
        bool o1 = ((unsigned)comp16[j1] != ci);
        bool o2 = ((unsigned)comp16[j2] != ci);
        unsigned es = o1 ? c[s].x : (o2 ? c[s].y : 0xFFFFFFFFu);
        unsigned bs = (!o1 && !o2) ? (c[s].y >> 16) : 0xFFFFu;
        e = umin32(e, es);
        bw = umin32(bw, bs);
      }
      if (e != 0xFFFFFFFFu) {
        unsigned j = e & 0xFFFFu, hv = e >> 16;
        unsigned cmn = umin32((unsigned)tid, j);
        unsigned cmx = (unsigned)tid + j - cmn;
        unsigned long long k64 =
            ((unsigned long long)hv << 20) | (unsigned long long)((cmn << 10) | cmx);
        atomicMin(&best64[ci], k64);
      }
      __syncthreads();  // B1: all exact candidates applied

      unsigned bestw = (unsigned)((best64[ci] >> 20) & 0xFFFFu);
      if (bw <= bestw) {
        unsigned slot = atomicAdd(&nfb_sh, 1u);
        fb[slot] = (unsigned short)tid;
      }
      __syncthreads();  // B2: nfb + fb visible

      unsigned nfb = nfb_sh;
      if (nfb) {
        unsigned cj[16];
        #pragma unroll
        for (int q = 0; q < 8; ++q) cj[q] = comp16[jb0 + q];
        #pragma unroll
        for (int q = 0; q < 8; ++q) cj[8 + q] = comp16[jb1 + q];
        for (unsigned k = (unsigned)wid; k < nfb; k += 16) {
          int frow = fb[k];
          unsigned fci = (unsigned)comp16[frow];
          uint4 ra = p[frow * 128 + lane];
          uint4 rb = p[frow * 128 + 64 + lane];
          unsigned key = 0xFFFFFFFFu;
          #define ENT(word, cl, ch, jb) { \
            unsigned klo = ((word) << 16) | (jb); \
            unsigned khi = ((word) & 0xFFFF0000u) | ((jb) + 1); \
            key = umin32(key, (cl) == fci ? 0xFFFFFFFFu : klo); \
            key = umin32(key, (ch) == fci ? 0xFFFFFFFFu : khi); }
          ENT(ra.x, cj[0],  cj[1],  jb0 + 0) ENT(ra.y, cj[2],  cj[3],  jb0 + 2)
          ENT(ra.z, cj[4],  cj[5],  jb0 + 4) ENT(ra.w, cj[6],  cj[7],  jb0 + 6)
          ENT(rb.x, cj[8],  cj[9],  jb1 + 0) ENT(rb.y, cj[10], cj[11], jb1 + 2)
          ENT(rb.z, cj[12], cj[13], jb1 + 4) ENT(rb.w, cj[14], cj[15], jb1 + 6)
          #undef ENT
          #define DPPMIN(ctrl) { \
            unsigned tv = (unsigned)__builtin_amdgcn_update_dpp((int)key, (int)key, (ctrl), 0xF, 0xF, false); \
            key = umin32(key, tv); }
          DPPMIN(0x111) DPPMIN(0x112) DPPMIN(0x114) DPPMIN(0x118)
          DPPMIN(0x142) DPPMIN(0x143)
          #undef DPPMIN
          if (lane == 63 && key != 0xFFFFFFFFu) {
            unsigned wv = key >> 16, v = key & 0xFFFFu;
            unsigned cmn = umin32((unsigned)frow, v);
            unsigned cmx = (unsigned)frow + v - cmn;
            unsigned long long k64 =
                ((unsigned long long)wv << 20) | (unsigned long long)((cmn << 10) | cmx);
            atomicMin(&best64[fci], k64);
          }
        }
        __syncthreads();  // B3: fallback atomics visible
      }
    }

    // ---- merge: hook, 2-cycle break, append ----
    unsigned long long bk = best64[tid];
    unsigned cold = comp16[tid];
    unsigned partner = (unsigned)tid;
    unsigned wb = 0;
    if (cold == (unsigned)tid && bk != BMAX) {
      wb = (unsigned)(bk >> 20) & 0xFFFFu;
      unsigned cmin = (unsigned)(bk >> 10) & 1023u;
      unsigned cmax = (unsigned)bk & 1023u;
      unsigned ca = comp16[cmin], cb = comp16[cmax];
      partner = (ca == (unsigned)tid) ? cb : ca;
      par[tid] = (unsigned short)partner;
    }
    __syncthreads();  // B4: hooks visible
    unsigned pp = par[partner];
    bool twoc = (partner != (unsigned)tid) && (pp == (unsigned)tid);
    bool winner = twoc && ((unsigned)tid < partner);
    bool append = (partner != (unsigned)tid) && !winner;
    __syncthreads();  // B5: all pp reads done before winner-fix writes
    if (winner) par[tid] = (unsigned short)tid;
    if (append) {
      unsigned slot = atomicAdd(&dcnt_sh, 1u);
      dl[slot] = __half2float(__ushort_as_half((unsigned short)wb));
    }
    __syncthreads();  // B6: par final for chase; dcnt visible
    if (dcnt_sh == NPTS - 1) break;

    unsigned x = cold;
    unsigned px = par[x];
    while (px != x) { x = px; px = par[x]; }
    __syncthreads();  // B7: chases done before state rewrite
    comp16[tid] = (unsigned short)x;
    par[tid] = (unsigned short)tid;
    best64[tid] = BMAX;
    if (tid == 0) nfb_sh = 0;
    __syncthreads();  // B8: state ready for next round
  }
  __syncthreads();

  // ---- hybrid bitonic sort: jj<64 via shfl, jj>=64 via LDS ----
  float v = dl[tid];
  for (int k = 2; k <= NPTS; k <<= 1) {
    bool up = ((tid & k) == 0);
    for (int jj = k >> 1; jj > 0; jj >>= 1) {
      float pv;
      if (jj >= 64) {
        __syncthreads();
        dl[tid] = v;
        __syncthreads();
        pv = dl[tid ^ jj];
      } else {
        pv = __shfl_xor(v, jj);
      }
      bool lower = ((tid & jj) == 0);
      v = (lower == up) ? fminf(v, pv) : fmaxf(v, pv);
    }
  }
  deaths_out[(size_t)cloud * NPTS + tid] = v;
}

// ---------------- fallback MSE kernel (small ws path) ----------------
__global__ __launch_bounds__(256) void mse_kernel(const float* __restrict__ a,
                                                  const float* __restrict__ b,
                                                  double* __restrict__ acc, int n4) {
  int i = blockIdx.x * blockDim.x + threadIdx.x;
  int stride = gridDim.x * blockDim.x;
  const float4* a4 = (const float4*)a;
  const float4* b4 = (const float4*)b;
  float s = 0.f;
  for (int k = i; k < n4; k += stride) {
    float4 va = a4[k], vb = b4[k];
    float dx = va.x - vb.x, dy = va.y - vb.y, dz = va.z - vb.z, dw = va.w - vb.w;
    s += dx * dx + dy * dy + dz * dz + dw * dw;
  }
  #pragma unroll
  for (int off = 32; off; off >>= 1) s += __shfl_xor(s, off);
  __shared__ float wsum[4];
  int lane = threadIdx.x & 63, wid = threadIdx.x >> 6;
  if (lane == 0) wsum[wid] = s;
  __syncthreads();
  if (threadIdx.x == 0)
    atomicAdd(acc, (double)(wsum[0] + wsum[1] + wsum[2] + wsum[3]));
}

// ---------------- fallback: fused Prim+sort from x (small ws) ----------------
__global__ __launch_bounds__(1024) void prim_kernel(const float* __restrict__ x1,
                                                    const float* __restrict__ x2,
                                                    float* __restrict__ sorted_out) {
  const int cloud = blockIdx.x;
  const int b = cloud & (BATCH - 1);
  const int src = cloud >> 4;
  const float* xbase = (src ? x2 : x1) + (size_t)b * NPTS * DIM;
  const int j = threadIdx.x;

  __shared__ float xi_sh[DIM];
  __shared__ float sq_sh[NPTS];
  __shared__ float redw[16];
  __shared__ int   redi[16];
  __shared__ float deaths[NPTS];

  const float4* xr = (const float4*)(xbase + (size_t)j * DIM);
  {
    float ax = 0.f, ay = 0.f, az = 0.f, aw = 0.f;
    #pragma unroll 8
    for (int m = 0; m < DIM / 4; ++m) {
      float4 v = xr[m];
      ax = fmaf(v.x, v.x, ax); ay = fmaf(v.y, v.y, ay);
      az = fmaf(v.z, v.z, az); aw = fmaf(v.w, v.w, aw);
    }
    sq_sh[j] = (ax + ay) + (az + aw);
  }
  const float sqj = sq_sh[j];

  float mind = BIGF;
  bool in_tree = (j == 0);
  int  cur = 0;

  for (int t = 0; t < NPTS - 1; ++t) {
    if (threadIdx.x < DIM / 4)
      ((float4*)xi_sh)[threadIdx.x] = ((const float4*)(xbase + (size_t)cur * DIM))[threadIdx.x];
    __syncthreads();

    const float4* xi4 = (const float4*)xi_sh;
    float ax = 0.f, ay = 0.f, az = 0.f, aw = 0.f;
    #pragma unroll 8
    for (int m = 0; m < DIM / 4; ++m) {
      float4 v = xr[m];
      float4 u = xi4[m];
      ax = fmaf(v.x, u.x, ax); ay = fmaf(v.y, u.y, ay);
      az = fmaf(v.z, u.z, az); aw = fmaf(v.w, u.w, aw);
    }
    float dot = (ax + ay) + (az + aw);
    float d2 = sq_sh[cur] + sqj - 2.f * dot;
    float d = sqrtf(fmaxf(d2, 0.f) + 1e-12f);
    mind = in_tree ? BIGF : fminf(mind, d);

    float w = mind;
    int idx = j;
    #pragma unroll
    for (int off = 32; off; off >>= 1) {
      float w2 = __shfl_xor(w, off);
      int i2 = __shfl_xor(idx, off);
      if (w2 < w || (w2 == w && i2 < idx)) { w = w2; idx = i2; }
    }
    int lane = j & 63, wid = j >> 6;
    if (lane == 0) { redw[wid] = w; redi[wid] = idx; }
    __syncthreads();

    float cw = redw[0];
    int ci = redi[0];
    #pragma unroll
    for (int q = 1; q < 16; ++q) {
      float w2 = redw[q]; int i2 = redi[q];
      if (w2 < cw || (w2 == cw && i2 < ci)) { cw = w2; ci = i2; }
    }
    if (j == ci) in_tree = true;
    if (j == 0)  deaths[t] = cw;
    cur = ci;
  }

  if (threadIdx.x == 0) deaths[NPTS - 1] = BIGF;
  __syncthreads();

  for (int k = 2; k <= NPTS; k <<= 1) {
    for (int jj = k >> 1; jj > 0; jj >>= 1) {
      int i = threadIdx.x;
      int l = i ^ jj;
      if (l > i) {
        float va = deaths[i], vb = deaths[l];
        bool up = ((i & k) == 0);
        if ((va > vb) == up) { deaths[i] = vb; deaths[l] = va; }
      }
      __syncthreads();
    }
  }
  sorted_out[(size_t)cloud * NPTS + threadIdx.x] = deaths[threadIdx.x];
}

// ---------------- final combine (sums the 128 MSE partials deterministically) ----------------
__global__ __launch_bounds__(1024) void final_kernel(const double* __restrict__ partials,
                                                     const float* __restrict__ sorted,
                                                     float* __restrict__ out, int npart) {
  int wid = threadIdx.x >> 6;
  int lane = threadIdx.x & 63;
  const float* s1 = sorted + (size_t)wid * NPTS;
  const float* s2 = sorted + (size_t)(BATCH + wid) * NPTS;
  float s = 0.f;
  for (int k = lane; k < NPTS; k += 64) {
    float dlt = s1[k] - s2[k];
    s += dlt * dlt;
  }
  #pragma unroll
  for (int off = 32; off; off >>= 1) s += __shfl_xor(s, off);
  __shared__ float part[16];
  __shared__ double dsum[128];
  if (threadIdx.x < (unsigned)npart) dsum[threadIdx.x] = partials[threadIdx.x];
  if (lane == 0) part[wid] = sqrtf(s);
  __syncthreads();
  if (threadIdx.x == 0) {
    float topo = 0.f;
    #pragma unroll
    for (int q = 0; q < 16; ++q) topo += part[q];
    double msum = 0.0;
    for (int q = 0; q < npart; ++q) msum += dsum[q];
    float mse = (float)(msum / (double)((size_t)BATCH * NPTS * DIM));
    out[0] = 1.0f * mse + 0.1f * topo;
  }
}

extern "C" void kernel_launch(void* const* d_in, const int* in_sizes, int n_in,
                              void* d_out, int out_size, void* d_ws, size_t ws_size,
                              hipStream_t stream) {
  const float* x1 = (const float*)d_in[0];
  const float* x2 = (const float*)d_in[1];
  double* partials = (double*)((char*)d_ws + PART_OFF);
  float* deaths    = (float*)((char*)d_ws + DEATHS_OFF);
  float* out       = (float*)d_out;

  if (ws_size >= WS_NEED) {
    unsigned short* Dmat = (unsigned short*)((char*)d_ws + D_OFF);
    unsigned short* xbf  = (unsigned short*)((char*)d_ws + XBF_OFF);
    float* sqg           = (float*)((char*)d_ws + SQ_OFF);
    unsigned long long* best = (unsigned long long*)((char*)d_ws + BEST_OFF);
    uint2* cand          = (uint2*)((char*)d_ws + CAND_OFF);

    prep_mse<<<dim3(NCLOUD, 8), 128, 0, stream>>>(x1, x2, xbf, sqg, best, partials);
    distmat_mfma<<<dim3(136, NCLOUD), 256, 0, stream>>>(xbf, sqg, Dmat, best, cand);
    boruvka_solve<<<NCLOUD, 1024, 0, stream>>>(Dmat, cand, best, deaths);
    final_kernel<<<1, 1024, 0, stream>>>(partials, deaths, out, 128);
  } else {
    hipMemsetAsync(d_ws, 0, 64, stream);
    double* mse_acc = (double*)d_ws;
    int n4 = (BATCH * NPTS * DIM) / 4;
    mse_kernel<<<1024, 256, 0, stream>>>(x1, x2, mse_acc, n4);
    prim_kernel<<<NCLOUD, 1024, 0, stream>>>(x1, x2, deaths);
    final_kernel<<<1, 1024, 0, stream>>>(mse_acc, deaths, out, 1);
  }
}